// Round 1
// baseline (468.053 us; speedup 1.0000x reference)
//
#include <hip/hip_runtime.h>
#include <cstdint>
#include <cstddef>

#define DEV __device__ __forceinline__

typedef __attribute__((ext_vector_type(4))) float f32x4;
typedef __attribute__((ext_vector_type(4))) unsigned int u32x4;
typedef __attribute__((ext_vector_type(2))) unsigned int u32x2;
typedef unsigned short ushort_t;

constexpr int NN  = 8192;   // decoder nodes
constexpr int MMM = 8192;   // encoder memory nodes
constexpr int DD  = 512;    // d_model
constexpr int DFF = 2048;   // ff hidden

// ---------- helpers ----------
DEV unsigned short f2bf(float f) {
  unsigned int u = __builtin_bit_cast(unsigned int, f);
  u += 0x7fffu + ((u >> 16) & 1u);           // round-to-nearest-even
  return (unsigned short)(u >> 16);
}
DEV float bflo(unsigned int u) { return __builtin_bit_cast(float, u << 16); }
DEV float bfhi(unsigned int u) { return __builtin_bit_cast(float, u & 0xffff0000u); }

DEV void gload_lds16(const void* g, void* l) {
  __builtin_amdgcn_global_load_lds((__attribute__((address_space(1))) void*)g,
                                   (__attribute__((address_space(3))) void*)l,
                                   16, 0, 0);
}

// ---------- weight transpose + bf16 convert: in [R][C] f32 -> out [C][R] bf16 ----------
__global__ void transw_kernel(const float* __restrict__ in, ushort_t* __restrict__ out,
                              int R, int C) {
  __shared__ float t[32][33];
  const int x0 = blockIdx.x * 32, y0 = blockIdx.y * 32;
  const int tx = threadIdx.x, ty = threadIdx.y;   // block (32,8)
#pragma unroll
  for (int i = 0; i < 4; ++i)
    t[ty + i * 8][tx] = in[(long)(y0 + ty + i * 8) * C + x0 + tx];
  __syncthreads();
#pragma unroll
  for (int i = 0; i < 4; ++i)
    out[(long)(x0 + ty + i * 8) * R + y0 + tx] = f2bf(t[tx][ty + i * 8]);
}

// ---------- f32 -> bf16 elementwise (4/thread) ----------
__global__ void tobf_kernel(const float* __restrict__ in, ushort_t* __restrict__ out, int n4) {
  int i = blockIdx.x * blockDim.x + threadIdx.x;
  if (i >= n4) return;
  f32x4 v = ((const f32x4*)in)[i];
  u32x2 o;
  o[0] = (unsigned)f2bf(v[0]) | ((unsigned)f2bf(v[1]) << 16);
  o[1] = (unsigned)f2bf(v[2]) | ((unsigned)f2bf(v[3]) << 16);
  ((u32x2*)out)[i] = o;
}

// ---------- LayerNorm: f32 in -> bf16 out, one wave per row of 512 ----------
__global__ __launch_bounds__(256)
void ln_kernel(const float* __restrict__ x, const float* __restrict__ g,
               const float* __restrict__ b, ushort_t* __restrict__ out) {
  const int row  = blockIdx.x * 4 + (threadIdx.x >> 6);
  const int lane = threadIdx.x & 63;
  const float* xr = x + (long)row * DD + lane * 8;
  float v[8];
  *(f32x4*)&v[0] = *(const f32x4*)&xr[0];
  *(f32x4*)&v[4] = *(const f32x4*)&xr[4];
  float s = 0.f, sq = 0.f;
#pragma unroll
  for (int i = 0; i < 8; ++i) { s += v[i]; sq += v[i] * v[i]; }
#pragma unroll
  for (int o = 1; o < 64; o <<= 1) { s += __shfl_xor(s, o); sq += __shfl_xor(sq, o); }
  const float mu   = s * (1.f / 512.f);
  const float var  = sq * (1.f / 512.f) - mu * mu;
  const float rstd = rsqrtf(var + 1e-6f);
  const float* gp = g + lane * 8;
  const float* bp = b + lane * 8;
  u32x4 o8;
#pragma unroll
  for (int u = 0; u < 4; ++u) {
    unsigned int lo = f2bf((v[2 * u]     - mu) * rstd * gp[2 * u]     + bp[2 * u]);
    unsigned int hi = f2bf((v[2 * u + 1] - mu) * rstd * gp[2 * u + 1] + bp[2 * u + 1]);
    o8[u] = lo | (hi << 16);
  }
  *(u32x4*)(out + (long)row * DD + lane * 8) = o8;
}

// ---------- bf16 MFMA GEMM: C[M,N] = A[M,K] @ Bt[N,K]^T + bias, fused epilogues ----------
// EPI 0: bf16 out (bias);  1: bf16 out (bias+relu);  2: f32 out (bias + residual add)
template <int EPI>
__global__ __launch_bounds__(256, 2)
void gemm_kernel(const ushort_t* __restrict__ A, const ushort_t* __restrict__ Bt,
                 const float* __restrict__ bias, const float* res,
                 float* outF, ushort_t* outB, int M, int N, int K) {
  __shared__ __align__(16) ushort_t sA[128 * 64];
  __shared__ __align__(16) ushort_t sB[128 * 64];
  const int tid  = threadIdx.x;
  const int lane = tid & 63;
  const int w    = tid >> 6;
  const int wr   = w >> 1, wc = w & 1;
  const long brow = (long)blockIdx.x * 128;
  const long bcol = (long)blockIdx.y * 128;
  const int r16 = lane & 15;
  const int kb8 = (lane >> 4) << 3;
  f32x4 acc[4][4] = {};

  for (int k0 = 0; k0 < K; k0 += 64) {
    __syncthreads();                       // previous readers done before overwrite
#pragma unroll
    for (int i = 0; i < 4; ++i) {
      const int c  = i * 256 + tid;
      const int wb = i * 256 + (tid & ~63);   // wave-uniform chunk base
      gload_lds16(A  + (brow + (c >> 3)) * (long)K + k0 + ((c & 7) << 3), &sA[(long)wb * 8]);
      gload_lds16(Bt + (bcol + (c >> 3)) * (long)K + k0 + ((c & 7) << 3), &sB[(long)wb * 8]);
    }
    __syncthreads();                       // vmcnt(0) drained here by compiler
#pragma unroll
    for (int kk = 0; kk < 64; kk += 32) {
      u32x4 af[4], bfr[4];
#pragma unroll
      for (int i = 0; i < 4; ++i)
        af[i] = *(const u32x4*)&sA[(wr * 64 + i * 16 + r16) * 64 + kk + kb8];
#pragma unroll
      for (int j = 0; j < 4; ++j)
        bfr[j] = *(const u32x4*)&sB[(wc * 64 + j * 16 + r16) * 64 + kk + kb8];
#pragma unroll
      for (int i = 0; i < 4; ++i)
#pragma unroll
        for (int j = 0; j < 4; ++j)
          asm("v_mfma_f32_16x16x32_bf16 %0, %1, %2, %0"
              : "+v"(acc[i][j]) : "v"(af[i]), "v"(bfr[j]));
    }
  }
  asm volatile("s_nop 7\n\ts_nop 7\n\ts_nop 7" ::);  // MFMA->VALU hazard guard (asm opaque to recognizer)

  const long orow = brow + wr * 64;
  const long ocol = bcol + wc * 64;
#pragma unroll
  for (int j = 0; j < 4; ++j) {
    const long c  = ocol + j * 16 + r16;
    const float bv = bias[c];
#pragma unroll
    for (int i = 0; i < 4; ++i) {
      const long r0 = orow + i * 16 + ((lane >> 4) << 2);
#pragma unroll
      for (int r = 0; r < 4; ++r) {
        float v = acc[i][j][r] + bv;
        const long idx = (r0 + r) * (long)N + c;
        if (EPI == 0)      outB[idx] = f2bf(v);
        else if (EPI == 1) outB[idx] = f2bf(fmaxf(v, 0.f));
        else               outF[idx] = v + res[idx];
      }
    }
  }
}

// ---------- CSR build (counting sort by dst) ----------
__global__ void zero_kernel(int* p, int n) {
  int i = blockIdx.x * blockDim.x + threadIdx.x;
  if (i < n) p[i] = 0;
}
__global__ void hist_kernel(const int* __restrict__ dst, int* __restrict__ counts, int E) {
  for (int e = blockIdx.x * blockDim.x + threadIdx.x; e < E; e += gridDim.x * blockDim.x)
    atomicAdd(&counts[dst[e]], 1);
}
__global__ void scan_kernel(const int* __restrict__ counts, int* __restrict__ rowstart,
                            int* __restrict__ cursor) {
  __shared__ int part[256];
  const int t = threadIdx.x;
  int loc[32];
  int s = 0;
  const int base = t * 32;
#pragma unroll
  for (int i = 0; i < 32; ++i) { loc[i] = counts[base + i]; s += loc[i]; }
  part[t] = s;
  __syncthreads();
  for (int off = 1; off < 256; off <<= 1) {
    int v2 = (t >= off) ? part[t - off] : 0;
    __syncthreads();
    part[t] += v2;
    __syncthreads();
  }
  int run = part[t] - s;   // exclusive prefix
#pragma unroll
  for (int i = 0; i < 32; ++i) { rowstart[base + i] = run; cursor[base + i] = run; run += loc[i]; }
  if (t == 255) rowstart[8192] = run;
}
__global__ void scatter_kernel(const int* __restrict__ src, const int* __restrict__ dst,
                               int* __restrict__ cursor, int* __restrict__ srcs, int E) {
  for (int e = blockIdx.x * blockDim.x + threadIdx.x; e < E; e += gridDim.x * blockDim.x) {
    const int p = atomicAdd(&cursor[dst[e]], 1);
    srcs[p] = src[e];
  }
}

// ---------- graph attention: one wave per dst node, register accumulation ----------
__global__ __launch_bounds__(256)
void attend_kernel(const int* __restrict__ rowstart, const int* __restrict__ srcs,
                   const ushort_t* __restrict__ qb, const ushort_t* __restrict__ kb,
                   const ushort_t* __restrict__ vb, ushort_t* __restrict__ ob) {
  const int d    = blockIdx.x * 4 + (threadIdx.x >> 6);
  const int lane = threadIdx.x & 63;           // lane covers cols lane*8..+7; head = lane>>3
  const int e0 = rowstart[d], e1 = rowstart[d + 1];
  u32x4 qv = *(const u32x4*)(qb + (long)d * DD + lane * 8);
  float q[8];
#pragma unroll
  for (int u = 0; u < 4; ++u) { q[2 * u] = bflo(qv[u]); q[2 * u + 1] = bfhi(qv[u]); }
  float acc[8] = {};
  float z = 0.f;
  for (int e = e0; e < e1; ++e) {
    const int s = srcs[e];
    const u32x4 kv = *(const u32x4*)(kb + (long)s * DD + lane * 8);
    float dot = 0.f;
#pragma unroll
    for (int u = 0; u < 4; ++u) dot += bflo(kv[u]) * q[2 * u] + bfhi(kv[u]) * q[2 * u + 1];
    dot += __shfl_xor(dot, 1);               // reduce over the 8 lanes of this head
    dot += __shfl_xor(dot, 2);
    dot += __shfl_xor(dot, 4);
    const float sc = __expf(fminf(fmaxf(dot * 0.125f, -10.f), 10.f));  // 1/sqrt(64)=0.125
    const u32x4 vv = *(const u32x4*)(vb + (long)s * DD + lane * 8);
#pragma unroll
    for (int u = 0; u < 4; ++u) { acc[2 * u] += sc * bflo(vv[u]); acc[2 * u + 1] += sc * bfhi(vv[u]); }
    z += sc;
  }
  const float inv = 1.f / z;
  u32x4 o;
#pragma unroll
  for (int u = 0; u < 4; ++u) {
    unsigned int lo = f2bf(acc[2 * u] * inv);
    unsigned int hi = f2bf(acc[2 * u + 1] * inv);
    o[u] = lo | (hi << 16);
  }
  *(u32x4*)(ob + (long)d * DD + lane * 8) = o;
}

// ---------- host orchestration ----------
extern "C" void kernel_launch(void* const* d_in, const int* in_sizes, int n_in,
                              void* d_out, int out_size, void* d_ws, size_t ws_size,
                              hipStream_t stream) {
  const float* x    = (const float*)d_in[0];
  const float* mem  = (const float*)d_in[1];
  const float* ln0g = (const float*)d_in[2];  const float* ln0b = (const float*)d_in[3];
  const float* ln1g = (const float*)d_in[4];  const float* ln1b = (const float*)d_in[5];
  const float* ln2g = (const float*)d_in[6];  const float* ln2b = (const float*)d_in[7];
  const float* Wq = (const float*)d_in[8];   const float* bq = (const float*)d_in[9];
  const float* Wk = (const float*)d_in[10];  const float* bk = (const float*)d_in[11];
  const float* Wv = (const float*)d_in[12];  const float* bv = (const float*)d_in[13];
  const float* Wo = (const float*)d_in[14];  const float* bo = (const float*)d_in[15];
  const float* W1 = (const float*)d_in[16];  const float* b1 = (const float*)d_in[17];
  const float* W2 = (const float*)d_in[18];  const float* b2 = (const float*)d_in[19];
  const int* src_self  = (const int*)d_in[20];
  const int* dst_self  = (const int*)d_in[21];
  const int* src_cross = (const int*)d_in[22];
  const int* dst_cross = (const int*)d_in[23];
  const int E = in_sizes[20];
  float* out = (float*)d_out;

  char* wsp = (char*)d_ws;
  auto alloc = [&](size_t bytes) {
    char* p = wsp;
    wsp += (bytes + 255) & ~(size_t)255;
    return p;
  };
  ushort_t* Wq_t = (ushort_t*)alloc((size_t)DD * DD * 2);
  ushort_t* Wk_t = (ushort_t*)alloc((size_t)DD * DD * 2);
  ushort_t* Wv_t = (ushort_t*)alloc((size_t)DD * DD * 2);
  ushort_t* Wo_t = (ushort_t*)alloc((size_t)DD * DD * 2);
  ushort_t* W1_t = (ushort_t*)alloc((size_t)DFF * DD * 2);
  ushort_t* W2_t = (ushort_t*)alloc((size_t)DD * DFF * 2);
  ushort_t* h_bf   = (ushort_t*)alloc((size_t)NN * DD * 2);
  ushort_t* mem_bf = (ushort_t*)alloc((size_t)MMM * DD * 2);
  ushort_t* q_bf   = (ushort_t*)alloc((size_t)NN * DD * 2);
  ushort_t* k_bf   = (ushort_t*)alloc((size_t)MMM * DD * 2);
  ushort_t* v_bf   = (ushort_t*)alloc((size_t)MMM * DD * 2);
  ushort_t* attn_bf= (ushort_t*)alloc((size_t)NN * DD * 2);
  ushort_t* ffh_bf = (ushort_t*)alloc((size_t)NN * DFF * 2);
  int* counts   = (int*)alloc(8192 * 4);
  int* rowstart = (int*)alloc(8193 * 4);
  int* cursor   = (int*)alloc(8192 * 4);
  int* srcs     = (int*)alloc((size_t)E * 4);

  const dim3 B256(256);

  // weights -> transposed bf16
  transw_kernel<<<dim3(16, 16), dim3(32, 8), 0, stream>>>(Wq, Wq_t, DD, DD);
  transw_kernel<<<dim3(16, 16), dim3(32, 8), 0, stream>>>(Wk, Wk_t, DD, DD);
  transw_kernel<<<dim3(16, 16), dim3(32, 8), 0, stream>>>(Wv, Wv_t, DD, DD);
  transw_kernel<<<dim3(16, 16), dim3(32, 8), 0, stream>>>(Wo, Wo_t, DD, DD);
  transw_kernel<<<dim3(64, 16), dim3(32, 8), 0, stream>>>(W1, W1_t, DD, DFF);
  transw_kernel<<<dim3(16, 64), dim3(32, 8), 0, stream>>>(W2, W2_t, DFF, DD);
  // mem -> bf16
  tobf_kernel<<<dim3(MMM * DD / 4 / 256), B256, 0, stream>>>(mem, mem_bf, MMM * DD / 4);

  auto gemm = [&](int mode, const ushort_t* Ap, const ushort_t* Btp, const float* biasp,
                  const float* resp, float* oF, ushort_t* oB, int M_, int N_, int K_) {
    dim3 g(M_ / 128, N_ / 128);
    if (mode == 0)
      gemm_kernel<0><<<g, B256, 0, stream>>>(Ap, Btp, biasp, resp, oF, oB, M_, N_, K_);
    else if (mode == 1)
      gemm_kernel<1><<<g, B256, 0, stream>>>(Ap, Btp, biasp, resp, oF, oB, M_, N_, K_);
    else
      gemm_kernel<2><<<g, B256, 0, stream>>>(Ap, Btp, biasp, resp, oF, oB, M_, N_, K_);
  };
  auto build_csr = [&](const int* sL, const int* dL) {
    zero_kernel<<<dim3(32), B256, 0, stream>>>(counts, 8192);
    hist_kernel<<<dim3(256), B256, 0, stream>>>(dL, counts, E);
    scan_kernel<<<dim3(1), B256, 0, stream>>>(counts, rowstart, cursor);
    scatter_kernel<<<dim3(256), B256, 0, stream>>>(sL, dL, cursor, srcs, E);
  };

  // ---- sublayer 0: self-attention ----
  ln_kernel<<<dim3(NN / 4), B256, 0, stream>>>(x, ln0g, ln0b, h_bf);
  gemm(0, h_bf, Wq_t, bq, nullptr, nullptr, q_bf, NN, DD, DD);
  gemm(0, h_bf, Wk_t, bk, nullptr, nullptr, k_bf, NN, DD, DD);
  gemm(0, h_bf, Wv_t, bv, nullptr, nullptr, v_bf, NN, DD, DD);
  build_csr(src_self, dst_self);
  attend_kernel<<<dim3(NN / 4), B256, 0, stream>>>(rowstart, srcs, q_bf, k_bf, v_bf, attn_bf);
  gemm(2, attn_bf, Wo_t, bo, x, out, nullptr, NN, DD, DD);          // out = x + attn@Wo+bo

  // ---- sublayer 1: cross-attention ----
  ln_kernel<<<dim3(NN / 4), B256, 0, stream>>>(out, ln1g, ln1b, h_bf);
  gemm(0, h_bf, Wq_t, bq, nullptr, nullptr, q_bf, NN, DD, DD);
  gemm(0, mem_bf, Wk_t, bk, nullptr, nullptr, k_bf, MMM, DD, DD);   // no LN on memory
  gemm(0, mem_bf, Wv_t, bv, nullptr, nullptr, v_bf, MMM, DD, DD);
  build_csr(src_cross, dst_cross);
  attend_kernel<<<dim3(NN / 4), B256, 0, stream>>>(rowstart, srcs, q_bf, k_bf, v_bf, attn_bf);
  gemm(2, attn_bf, Wo_t, bo, out, out, nullptr, NN, DD, DD);        // out += attn@Wo+bo

  // ---- sublayer 2: feed-forward ----
  ln_kernel<<<dim3(NN / 4), B256, 0, stream>>>(out, ln2g, ln2b, h_bf);
  gemm(1, h_bf, W1_t, b1, nullptr, nullptr, ffh_bf, NN, DFF, DD);   // relu, bf16 out
  gemm(2, ffh_bf, W2_t, b2, out, out, nullptr, NN, DD, DFF);        // out += ff@W2+b2

  (void)n_in; (void)out_size; (void)ws_size; (void)in_sizes;
}

// Round 2
// 411.197 us; speedup vs baseline: 1.1383x; 1.1383x over previous
//
#include <hip/hip_runtime.h>
#include <cstdint>
#include <cstddef>

#define DEV __device__ __forceinline__

typedef __attribute__((ext_vector_type(4))) float f32x4;
typedef __attribute__((ext_vector_type(4))) unsigned int u32x4;
typedef __attribute__((ext_vector_type(2))) unsigned int u32x2;
typedef unsigned short ushort_t;

constexpr int NN  = 8192;   // decoder nodes
constexpr int MMM = 8192;   // encoder memory nodes
constexpr int DD  = 512;    // d_model
constexpr int DFF = 2048;   // ff hidden

// ---------- helpers ----------
DEV unsigned short f2bf(float f) {
  unsigned int u = __builtin_bit_cast(unsigned int, f);
  u += 0x7fffu + ((u >> 16) & 1u);           // round-to-nearest-even
  return (unsigned short)(u >> 16);
}
DEV float bflo(unsigned int u) { return __builtin_bit_cast(float, u << 16); }
DEV float bfhi(unsigned int u) { return __builtin_bit_cast(float, u & 0xffff0000u); }

DEV void gload_lds16(const void* g, void* l) {
  __builtin_amdgcn_global_load_lds((__attribute__((address_space(1))) void*)g,
                                   (__attribute__((address_space(3))) void*)l,
                                   16, 0, 0);
}

// ---------- weight transpose + bf16 convert: in [R][C] f32 -> out [C][R] bf16 ----------
__global__ void transw_kernel(const float* __restrict__ in, ushort_t* __restrict__ out,
                              int R, int C) {
  __shared__ float t[32][33];
  const int x0 = blockIdx.x * 32, y0 = blockIdx.y * 32;
  const int tx = threadIdx.x, ty = threadIdx.y;   // block (32,8)
#pragma unroll
  for (int i = 0; i < 4; ++i)
    t[ty + i * 8][tx] = in[(long)(y0 + ty + i * 8) * C + x0 + tx];
  __syncthreads();
#pragma unroll
  for (int i = 0; i < 4; ++i)
    out[(long)(x0 + ty + i * 8) * R + y0 + tx] = f2bf(t[tx][ty + i * 8]);
}

// batched 512x512 transpose (4 matrices in one dispatch, blockIdx.z selects)
struct TW4 {
  const float* in0; const float* in1; const float* in2; const float* in3;
  ushort_t* o0; ushort_t* o1; ushort_t* o2; ushort_t* o3;
};
__global__ void transw4_kernel(TW4 p) {
  const float* in; ushort_t* out;
  switch (blockIdx.z) {
    case 0:  in = p.in0; out = p.o0; break;
    case 1:  in = p.in1; out = p.o1; break;
    case 2:  in = p.in2; out = p.o2; break;
    default: in = p.in3; out = p.o3; break;
  }
  __shared__ float t[32][33];
  const int x0 = blockIdx.x * 32, y0 = blockIdx.y * 32;
  const int tx = threadIdx.x, ty = threadIdx.y;   // block (32,8)
#pragma unroll
  for (int i = 0; i < 4; ++i)
    t[ty + i * 8][tx] = in[(long)(y0 + ty + i * 8) * 512 + x0 + tx];
  __syncthreads();
#pragma unroll
  for (int i = 0; i < 4; ++i)
    out[(long)(x0 + ty + i * 8) * 512 + y0 + tx] = f2bf(t[tx][ty + i * 8]);
}

// ---------- f32 -> bf16 elementwise (4/thread) ----------
__global__ void tobf_kernel(const float* __restrict__ in, ushort_t* __restrict__ out, int n4) {
  int i = blockIdx.x * blockDim.x + threadIdx.x;
  if (i >= n4) return;
  f32x4 v = ((const f32x4*)in)[i];
  u32x2 o;
  o[0] = (unsigned)f2bf(v[0]) | ((unsigned)f2bf(v[1]) << 16);
  o[1] = (unsigned)f2bf(v[2]) | ((unsigned)f2bf(v[3]) << 16);
  ((u32x2*)out)[i] = o;
}

// ---------- concat q/k/v biases into one [1536] vector ----------
__global__ void biascat_kernel(const float* __restrict__ bq, const float* __restrict__ bk,
                               const float* __restrict__ bv, float* __restrict__ o) {
  const int i = blockIdx.x * blockDim.x + threadIdx.x;
  if (i >= 1536) return;
  o[i] = (i < 512) ? bq[i] : ((i < 1024) ? bk[i - 512] : bv[i - 1024]);
}

// ---------- LayerNorm: f32 in -> bf16 out, one wave per row of 512 ----------
__global__ __launch_bounds__(256)
void ln_kernel(const float* __restrict__ x, const float* __restrict__ g,
               const float* __restrict__ b, ushort_t* __restrict__ out) {
  const int row  = blockIdx.x * 4 + (threadIdx.x >> 6);
  const int lane = threadIdx.x & 63;
  const float* xr = x + (long)row * DD + lane * 8;
  float v[8];
  *(f32x4*)&v[0] = *(const f32x4*)&xr[0];
  *(f32x4*)&v[4] = *(const f32x4*)&xr[4];
  float s = 0.f, sq = 0.f;
#pragma unroll
  for (int i = 0; i < 8; ++i) { s += v[i]; sq += v[i] * v[i]; }
#pragma unroll
  for (int o = 1; o < 64; o <<= 1) { s += __shfl_xor(s, o); sq += __shfl_xor(sq, o); }
  const float mu   = s * (1.f / 512.f);
  const float var  = sq * (1.f / 512.f) - mu * mu;
  const float rstd = rsqrtf(var + 1e-6f);
  const float* gp = g + lane * 8;
  const float* bp = b + lane * 8;
  u32x4 o8;
#pragma unroll
  for (int u = 0; u < 4; ++u) {
    unsigned int lo = f2bf((v[2 * u]     - mu) * rstd * gp[2 * u]     + bp[2 * u]);
    unsigned int hi = f2bf((v[2 * u + 1] - mu) * rstd * gp[2 * u + 1] + bp[2 * u + 1]);
    o8[u] = lo | (hi << 16);
  }
  *(u32x4*)(out + (long)row * DD + lane * 8) = o8;
}

// ---------- bf16 MFMA GEMM: C[M,N] = A[M,K] @ Bt[N,K]^T + bias, fused epilogues ----------
// EPI 0: bf16 out (bias);  1: bf16 out (bias+relu);  2: f32 out (bias + residual add)
template <int EPI>
__global__ __launch_bounds__(256, 2)
void gemm_kernel(const ushort_t* __restrict__ A, const ushort_t* __restrict__ Bt,
                 const float* __restrict__ bias, const float* res,
                 float* outF, ushort_t* outB, int M, int N, int K) {
  __shared__ __align__(16) ushort_t sA[128 * 64];
  __shared__ __align__(16) ushort_t sB[128 * 64];
  const int tid  = threadIdx.x;
  const int lane = tid & 63;
  const int w    = tid >> 6;
  const int wr   = w >> 1, wc = w & 1;
  const long brow = (long)blockIdx.x * 128;
  const long bcol = (long)blockIdx.y * 128;
  const int r16 = lane & 15;
  const int kb8 = (lane >> 4) << 3;
  f32x4 acc[4][4] = {};

  for (int k0 = 0; k0 < K; k0 += 64) {
    __syncthreads();                       // previous readers done before overwrite
#pragma unroll
    for (int i = 0; i < 4; ++i) {
      const int c  = i * 256 + tid;
      const int wb = i * 256 + (tid & ~63);   // wave-uniform chunk base
      gload_lds16(A  + (brow + (c >> 3)) * (long)K + k0 + ((c & 7) << 3), &sA[(long)wb * 8]);
      gload_lds16(Bt + (bcol + (c >> 3)) * (long)K + k0 + ((c & 7) << 3), &sB[(long)wb * 8]);
    }
    __syncthreads();                       // vmcnt(0) drained here by compiler
#pragma unroll
    for (int kk = 0; kk < 64; kk += 32) {
      u32x4 af[4], bfr[4];
#pragma unroll
      for (int i = 0; i < 4; ++i)
        af[i] = *(const u32x4*)&sA[(wr * 64 + i * 16 + r16) * 64 + kk + kb8];
#pragma unroll
      for (int j = 0; j < 4; ++j)
        bfr[j] = *(const u32x4*)&sB[(wc * 64 + j * 16 + r16) * 64 + kk + kb8];
#pragma unroll
      for (int i = 0; i < 4; ++i)
#pragma unroll
        for (int j = 0; j < 4; ++j)
          asm("v_mfma_f32_16x16x32_bf16 %0, %1, %2, %0"
              : "+v"(acc[i][j]) : "v"(af[i]), "v"(bfr[j]));
    }
  }
  asm volatile("s_nop 7\n\ts_nop 7\n\ts_nop 7" ::);  // MFMA->VALU hazard guard

  const long orow = brow + wr * 64;
  const long ocol = bcol + wc * 64;
#pragma unroll
  for (int j = 0; j < 4; ++j) {
    const long c  = ocol + j * 16 + r16;
    const float bv = bias[c];
#pragma unroll
    for (int i = 0; i < 4; ++i) {
      const long r0 = orow + i * 16 + ((lane >> 4) << 2);
#pragma unroll
      for (int r = 0; r < 4; ++r) {
        float v = acc[i][j][r] + bv;
        const long idx = (r0 + r) * (long)N + c;
        if (EPI == 0)      outB[idx] = f2bf(v);
        else if (EPI == 1) outB[idx] = f2bf(fmaxf(v, 0.f));
        else               outF[idx] = v + res[idx];
      }
    }
  }
}

// ---------- CSR build (counting sort by dst), both graphs fused ----------
__global__ void zero_kernel(int* p, int n) {
  int i = blockIdx.x * blockDim.x + threadIdx.x;
  if (i < n) p[i] = 0;
}
__global__ void hist2_kernel(const int* __restrict__ d0, const int* __restrict__ d1,
                             int* __restrict__ counts2, int E) {
  const int* d = blockIdx.y ? d1 : d0;
  int* c = counts2 + blockIdx.y * 8192;
  for (int e = blockIdx.x * blockDim.x + threadIdx.x; e < E; e += gridDim.x * blockDim.x)
    atomicAdd(&c[d[e]], 1);
}
__global__ void scan2_kernel(const int* __restrict__ counts2, int* __restrict__ rowstart2,
                             int* __restrict__ cursor2) {
  const int* counts = counts2 + blockIdx.x * 8192;
  int* rowstart = rowstart2 + blockIdx.x * 8193;
  int* cursor   = cursor2 + blockIdx.x * 8192;
  __shared__ int part[256];
  const int t = threadIdx.x;
  int loc[32];
  int s = 0;
  const int base = t * 32;
#pragma unroll
  for (int i = 0; i < 32; ++i) { loc[i] = counts[base + i]; s += loc[i]; }
  part[t] = s;
  __syncthreads();
  for (int off = 1; off < 256; off <<= 1) {
    int v2 = (t >= off) ? part[t - off] : 0;
    __syncthreads();
    part[t] += v2;
    __syncthreads();
  }
  int run = part[t] - s;   // exclusive prefix
#pragma unroll
  for (int i = 0; i < 32; ++i) { rowstart[base + i] = run; cursor[base + i] = run; run += loc[i]; }
  if (t == 255) rowstart[8192] = run;
}
__global__ void scatter2_kernel(const int* __restrict__ s0, const int* __restrict__ d0,
                                const int* __restrict__ s1, const int* __restrict__ d1,
                                int* __restrict__ cursor2,
                                int* __restrict__ o0, int* __restrict__ o1, int E) {
  const int* s = blockIdx.y ? s1 : s0;
  const int* d = blockIdx.y ? d1 : d0;
  int* cur = cursor2 + blockIdx.y * 8192;
  int* o   = blockIdx.y ? o1 : o0;
  for (int e = blockIdx.x * blockDim.x + threadIdx.x; e < E; e += gridDim.x * blockDim.x) {
    const int p = atomicAdd(&cur[d[e]], 1);
    o[p] = s[e];
  }
}

// ---------- graph attention: one wave per dst node, 1-deep prefetch pipeline ----------
__global__ __launch_bounds__(256)
void attend_kernel(const int* __restrict__ rowstart, const int* __restrict__ srcs,
                   const ushort_t* __restrict__ qb, int qs,
                   const ushort_t* __restrict__ kb, const ushort_t* __restrict__ vb, int ks,
                   ushort_t* __restrict__ ob) {
  const int d    = blockIdx.x * 4 + (threadIdx.x >> 6);
  const int lane = threadIdx.x & 63;           // lane covers cols lane*8..+7; head = lane>>3
  const int e0 = rowstart[d], e1 = rowstart[d + 1];
  const u32x4 qv = *(const u32x4*)(qb + (long)d * qs + lane * 8);
  float q[8];
#pragma unroll
  for (int u = 0; u < 4; ++u) { q[2 * u] = bflo(qv[u]); q[2 * u + 1] = bfhi(qv[u]); }
  float acc[8] = {};
  float z = 0.f;
  if (e1 > e0) {
    const int loff = lane * 8;
    int s_cur = srcs[e0];
    int s_nxt = (e0 + 1 < e1) ? srcs[e0 + 1] : s_cur;
    u32x4 kv = *(const u32x4*)(kb + (long)s_cur * ks + loff);
    u32x4 vv = *(const u32x4*)(vb + (long)s_cur * ks + loff);
    for (int e = e0; e < e1; ++e) {
      // issue next edge's gathers BEFORE the current reduce chain (1-deep pipeline)
      const u32x4 kv_n = *(const u32x4*)(kb + (long)s_nxt * ks + loff);
      const u32x4 vv_n = *(const u32x4*)(vb + (long)s_nxt * ks + loff);
      const int s_n2 = (e + 2 < e1) ? srcs[e + 2] : s_nxt;
      float dot = 0.f;
#pragma unroll
      for (int u = 0; u < 4; ++u) dot += bflo(kv[u]) * q[2 * u] + bfhi(kv[u]) * q[2 * u + 1];
      dot += __shfl_xor(dot, 1);               // reduce over the 8 lanes of this head
      dot += __shfl_xor(dot, 2);
      dot += __shfl_xor(dot, 4);
      const float sc = __expf(fminf(fmaxf(dot * 0.125f, -10.f), 10.f));  // 1/sqrt(64)=0.125
#pragma unroll
      for (int u = 0; u < 4; ++u) { acc[2 * u] += sc * bflo(vv[u]); acc[2 * u + 1] += sc * bfhi(vv[u]); }
      z += sc;
      kv = kv_n; vv = vv_n; s_nxt = s_n2;
    }
  }
  const float inv = 1.f / z;
  u32x4 o;
#pragma unroll
  for (int u = 0; u < 4; ++u) {
    unsigned int lo = f2bf(acc[2 * u] * inv);
    unsigned int hi = f2bf(acc[2 * u + 1] * inv);
    o[u] = lo | (hi << 16);
  }
  *(u32x4*)(ob + (long)d * DD + lane * 8) = o;
}

// ---------- host orchestration ----------
extern "C" void kernel_launch(void* const* d_in, const int* in_sizes, int n_in,
                              void* d_out, int out_size, void* d_ws, size_t ws_size,
                              hipStream_t stream) {
  const float* x    = (const float*)d_in[0];
  const float* mem  = (const float*)d_in[1];
  const float* ln0g = (const float*)d_in[2];  const float* ln0b = (const float*)d_in[3];
  const float* ln1g = (const float*)d_in[4];  const float* ln1b = (const float*)d_in[5];
  const float* ln2g = (const float*)d_in[6];  const float* ln2b = (const float*)d_in[7];
  const float* Wq = (const float*)d_in[8];   const float* bq = (const float*)d_in[9];
  const float* Wk = (const float*)d_in[10];  const float* bk = (const float*)d_in[11];
  const float* Wv = (const float*)d_in[12];  const float* bv = (const float*)d_in[13];
  const float* Wo = (const float*)d_in[14];  const float* bo = (const float*)d_in[15];
  const float* W1 = (const float*)d_in[16];  const float* b1 = (const float*)d_in[17];
  const float* W2 = (const float*)d_in[18];  const float* b2 = (const float*)d_in[19];
  const int* src_self  = (const int*)d_in[20];
  const int* dst_self  = (const int*)d_in[21];
  const int* src_cross = (const int*)d_in[22];
  const int* dst_cross = (const int*)d_in[23];
  const int E = in_sizes[20];
  float* out = (float*)d_out;

  char* wsp = (char*)d_ws;
  auto alloc = [&](size_t bytes) {
    char* p = wsp;
    wsp += (bytes + 255) & ~(size_t)255;
    return p;
  };
  // weights: Wqkv_t rows 0-511=Wq^T, 512-1023=Wk^T, 1024-1535=Wv^T (all [n][k], k=512)
  ushort_t* Wqkv_t = (ushort_t*)alloc((size_t)1536 * 512 * 2);
  ushort_t* Wo_t   = (ushort_t*)alloc((size_t)512 * 512 * 2);
  ushort_t* W1_t   = (ushort_t*)alloc((size_t)DFF * DD * 2);
  ushort_t* W2_t   = (ushort_t*)alloc((size_t)DD * DFF * 2);
  float*    bqkv   = (float*)alloc(1536 * 4);
  ushort_t* h_bf   = (ushort_t*)alloc((size_t)NN * DD * 2);
  ushort_t* mem_bf = (ushort_t*)alloc((size_t)MMM * DD * 2);
  ushort_t* buf1   = (ushort_t*)alloc((size_t)NN * DFF * 2);  // 32MB arena: qkv / q1+kv / ffh
  ushort_t* attn_bf= (ushort_t*)alloc((size_t)NN * DD * 2);
  int* counts2   = (int*)alloc(2 * 8192 * 4);
  int* rowstart2 = (int*)alloc(2 * 8193 * 4);
  int* cursor2   = (int*)alloc(2 * 8192 * 4);
  int* srcsA     = (int*)alloc((size_t)E * 4);
  int* srcsB     = (int*)alloc((size_t)E * 4);

  const dim3 B256(256);

  // ---- prep: weights, mem cast, both CSRs (input-only deps) ----
  TW4 tw{Wq, Wk, Wv, Wo, Wqkv_t, Wqkv_t + 512 * 512, Wqkv_t + 1024 * 512, Wo_t};
  transw4_kernel<<<dim3(16, 16, 4), dim3(32, 8), 0, stream>>>(tw);
  transw_kernel<<<dim3(64, 16), dim3(32, 8), 0, stream>>>(W1, W1_t, DD, DFF);
  transw_kernel<<<dim3(16, 64), dim3(32, 8), 0, stream>>>(W2, W2_t, DFF, DD);
  biascat_kernel<<<dim3(6), B256, 0, stream>>>(bq, bk, bv, bqkv);
  tobf_kernel<<<dim3(MMM * DD / 4 / 256), B256, 0, stream>>>(mem, mem_bf, MMM * DD / 4);
  zero_kernel<<<dim3(64), B256, 0, stream>>>(counts2, 2 * 8192);
  hist2_kernel<<<dim3(256, 2), B256, 0, stream>>>(dst_self, dst_cross, counts2, E);
  scan2_kernel<<<dim3(2), B256, 0, stream>>>(counts2, rowstart2, cursor2);
  scatter2_kernel<<<dim3(256, 2), B256, 0, stream>>>(src_self, dst_self, src_cross, dst_cross,
                                                     cursor2, srcsA, srcsB, E);

  auto gemm = [&](int mode, const ushort_t* Ap, const ushort_t* Btp, const float* biasp,
                  const float* resp, float* oF, ushort_t* oB, int M_, int N_, int K_) {
    dim3 g(M_ / 128, N_ / 128);
    if (mode == 0)
      gemm_kernel<0><<<g, B256, 0, stream>>>(Ap, Btp, biasp, resp, oF, oB, M_, N_, K_);
    else if (mode == 1)
      gemm_kernel<1><<<g, B256, 0, stream>>>(Ap, Btp, biasp, resp, oF, oB, M_, N_, K_);
    else
      gemm_kernel<2><<<g, B256, 0, stream>>>(Ap, Btp, biasp, resp, oF, oB, M_, N_, K_);
  };

  // ---- sublayer 0: self-attention ----
  ln_kernel<<<dim3(NN / 4), B256, 0, stream>>>(x, ln0g, ln0b, h_bf);
  gemm(0, h_bf, Wqkv_t, bqkv, nullptr, nullptr, buf1, NN, 1536, DD);   // fused q|k|v
  attend_kernel<<<dim3(NN / 4), B256, 0, stream>>>(rowstart2, srcsA,
      buf1, 1536, buf1 + 512, buf1 + 1024, 1536, attn_bf);
  gemm(2, attn_bf, Wo_t, bo, x, out, nullptr, NN, DD, DD);             // out = x + attn@Wo+bo

  // ---- sublayer 1: cross-attention ----
  ln_kernel<<<dim3(NN / 4), B256, 0, stream>>>(out, ln1g, ln1b, h_bf);
  {
    ushort_t* q1 = buf1;                       // [8192][512]
    ushort_t* kv = buf1 + (size_t)NN * 512;    // [8192][1024] (k|v)
    gemm(0, h_bf, Wqkv_t, bqkv, nullptr, nullptr, q1, NN, 512, DD);                    // q only
    gemm(0, mem_bf, Wqkv_t + 512 * 512, bqkv + 512, nullptr, nullptr, kv, MMM, 1024, DD); // k|v (no LN)
    attend_kernel<<<dim3(NN / 4), B256, 0, stream>>>(rowstart2 + 8193, srcsB,
        q1, 512, kv, kv + 512, 1024, attn_bf);
  }
  gemm(2, attn_bf, Wo_t, bo, out, out, nullptr, NN, DD, DD);           // out += attn@Wo+bo

  // ---- sublayer 2: feed-forward ----
  ln_kernel<<<dim3(NN / 4), B256, 0, stream>>>(out, ln2g, ln2b, h_bf);
  gemm(1, h_bf, W1_t, b1, nullptr, nullptr, buf1, NN, DFF, DD);        // relu, bf16 out
  gemm(2, buf1, W2_t, b2, out, out, nullptr, NN, DD, DFF);             // out += ff@W2+b2

  (void)n_in; (void)out_size; (void)ws_size; (void)in_sizes;
}

// Round 3
// 378.832 us; speedup vs baseline: 1.2355x; 1.0854x over previous
//
#include <hip/hip_runtime.h>
#include <cstdint>
#include <cstddef>

#define DEV __device__ __forceinline__

typedef __attribute__((ext_vector_type(4))) float f32x4;
typedef __attribute__((ext_vector_type(2))) float f32x2;
typedef __attribute__((ext_vector_type(4))) unsigned int u32x4;
typedef __attribute__((ext_vector_type(2))) unsigned int u32x2;
typedef unsigned short ushort_t;

constexpr int NN  = 8192;   // decoder nodes
constexpr int MMM = 8192;   // encoder memory nodes
constexpr int DD  = 512;    // d_model
constexpr int DFF = 2048;   // ff hidden

// ---------- helpers ----------
DEV unsigned short f2bf(float f) {
  unsigned int u = __builtin_bit_cast(unsigned int, f);
  u += 0x7fffu + ((u >> 16) & 1u);           // round-to-nearest-even
  return (unsigned short)(u >> 16);
}
DEV float bflo(unsigned int u) { return __builtin_bit_cast(float, u << 16); }
DEV float bfhi(unsigned int u) { return __builtin_bit_cast(float, u & 0xffff0000u); }

DEV void gload_lds16(const void* g, void* l) {
  __builtin_amdgcn_global_load_lds((__attribute__((address_space(1))) void*)g,
                                   (__attribute__((address_space(3))) void*)l,
                                   16, 0, 0);
}

// ---------- weight transpose + bf16 convert: in [R][C] f32 -> out [C][R] bf16 ----------
__global__ void transw_kernel(const float* __restrict__ in, ushort_t* __restrict__ out,
                              int R, int C) {
  __shared__ float t[32][33];
  const int x0 = blockIdx.x * 32, y0 = blockIdx.y * 32;
  const int tx = threadIdx.x, ty = threadIdx.y;   // block (32,8)
#pragma unroll
  for (int i = 0; i < 4; ++i)
    t[ty + i * 8][tx] = in[(long)(y0 + ty + i * 8) * C + x0 + tx];
  __syncthreads();
#pragma unroll
  for (int i = 0; i < 4; ++i)
    out[(long)(x0 + ty + i * 8) * R + y0 + tx] = f2bf(t[tx][ty + i * 8]);
}

// batched 512x512 transpose (4 matrices in one dispatch, blockIdx.z selects)
struct TW4 {
  const float* in0; const float* in1; const float* in2; const float* in3;
  ushort_t* o0; ushort_t* o1; ushort_t* o2; ushort_t* o3;
};
__global__ void transw4_kernel(TW4 p) {
  const float* in; ushort_t* out;
  switch (blockIdx.z) {
    case 0:  in = p.in0; out = p.o0; break;
    case 1:  in = p.in1; out = p.o1; break;
    case 2:  in = p.in2; out = p.o2; break;
    default: in = p.in3; out = p.o3; break;
  }
  __shared__ float t[32][33];
  const int x0 = blockIdx.x * 32, y0 = blockIdx.y * 32;
  const int tx = threadIdx.x, ty = threadIdx.y;   // block (32,8)
#pragma unroll
  for (int i = 0; i < 4; ++i)
    t[ty + i * 8][tx] = in[(long)(y0 + ty + i * 8) * 512 + x0 + tx];
  __syncthreads();
#pragma unroll
  for (int i = 0; i < 4; ++i)
    out[(long)(x0 + ty + i * 8) * 512 + y0 + tx] = f2bf(t[tx][ty + i * 8]);
}

// ---------- f32 -> bf16 elementwise (4/thread) ----------
__global__ void tobf_kernel(const float* __restrict__ in, ushort_t* __restrict__ out, int n4) {
  int i = blockIdx.x * blockDim.x + threadIdx.x;
  if (i >= n4) return;
  f32x4 v = ((const f32x4*)in)[i];
  u32x2 o;
  o[0] = (unsigned)f2bf(v[0]) | ((unsigned)f2bf(v[1]) << 16);
  o[1] = (unsigned)f2bf(v[2]) | ((unsigned)f2bf(v[3]) << 16);
  ((u32x2*)out)[i] = o;
}

// ---------- concat q/k/v biases into one [1536] vector ----------
__global__ void biascat_kernel(const float* __restrict__ bq, const float* __restrict__ bk,
                               const float* __restrict__ bv, float* __restrict__ o) {
  const int i = blockIdx.x * blockDim.x + threadIdx.x;
  if (i >= 1536) return;
  o[i] = (i < 512) ? bq[i] : ((i < 1024) ? bk[i - 512] : bv[i - 1024]);
}

// ---------- LayerNorm: f32 in -> bf16 out, one wave per row of 512 ----------
__global__ __launch_bounds__(256)
void ln_kernel(const float* __restrict__ x, const float* __restrict__ g,
               const float* __restrict__ b, ushort_t* __restrict__ out) {
  const int row  = blockIdx.x * 4 + (threadIdx.x >> 6);
  const int lane = threadIdx.x & 63;
  const float* xr = x + (long)row * DD + lane * 8;
  float v[8];
  *(f32x4*)&v[0] = *(const f32x4*)&xr[0];
  *(f32x4*)&v[4] = *(const f32x4*)&xr[4];
  float s = 0.f, sq = 0.f;
#pragma unroll
  for (int i = 0; i < 8; ++i) { s += v[i]; sq += v[i] * v[i]; }
#pragma unroll
  for (int o = 1; o < 64; o <<= 1) { s += __shfl_xor(s, o); sq += __shfl_xor(sq, o); }
  const float mu   = s * (1.f / 512.f);
  const float var  = sq * (1.f / 512.f) - mu * mu;
  const float rstd = rsqrtf(var + 1e-6f);
  const float* gp = g + lane * 8;
  const float* bp = b + lane * 8;
  u32x4 o8;
#pragma unroll
  for (int u = 0; u < 4; ++u) {
    unsigned int lo = f2bf((v[2 * u]     - mu) * rstd * gp[2 * u]     + bp[2 * u]);
    unsigned int hi = f2bf((v[2 * u + 1] - mu) * rstd * gp[2 * u + 1] + bp[2 * u + 1]);
    o8[u] = lo | (hi << 16);
  }
  *(u32x4*)(out + (long)row * DD + lane * 8) = o8;
}

// ---------- bf16 MFMA GEMM 128x128 tile: C[M,N] = A @ Bt^T + bias ----------
// EPI 0: bf16 out (bias);  1: bf16 out (bias+relu);  2: f32 out (bias + residual add)
template <int EPI>
__global__ __launch_bounds__(256, 2)
void gemm_kernel(const ushort_t* __restrict__ A, const ushort_t* __restrict__ Bt,
                 const float* __restrict__ bias, const float* res,
                 float* outF, ushort_t* outB, int M, int N, int K) {
  __shared__ __align__(16) ushort_t sA[128 * 64];
  __shared__ __align__(16) ushort_t sB[128 * 64];
  const int tid  = threadIdx.x;
  const int lane = tid & 63;
  const int w    = tid >> 6;
  const int wr   = w >> 1, wc = w & 1;
  const long brow = (long)blockIdx.x * 128;
  const long bcol = (long)blockIdx.y * 128;
  const int r16 = lane & 15;
  const int kb8 = (lane >> 4) << 3;
  f32x4 acc[4][4] = {};

  for (int k0 = 0; k0 < K; k0 += 64) {
    __syncthreads();
#pragma unroll
    for (int i = 0; i < 4; ++i) {
      const int c  = i * 256 + tid;
      const int wb = i * 256 + (tid & ~63);   // wave-uniform chunk base
      gload_lds16(A  + (brow + (c >> 3)) * (long)K + k0 + ((c & 7) << 3), &sA[(long)wb * 8]);
      gload_lds16(Bt + (bcol + (c >> 3)) * (long)K + k0 + ((c & 7) << 3), &sB[(long)wb * 8]);
    }
    __syncthreads();
#pragma unroll
    for (int kk = 0; kk < 64; kk += 32) {
      u32x4 af[4], bfr[4];
#pragma unroll
      for (int i = 0; i < 4; ++i)
        af[i] = *(const u32x4*)&sA[(wr * 64 + i * 16 + r16) * 64 + kk + kb8];
#pragma unroll
      for (int j = 0; j < 4; ++j)
        bfr[j] = *(const u32x4*)&sB[(wc * 64 + j * 16 + r16) * 64 + kk + kb8];
#pragma unroll
      for (int i = 0; i < 4; ++i)
#pragma unroll
        for (int j = 0; j < 4; ++j)
          asm("v_mfma_f32_16x16x32_bf16 %0, %1, %2, %0"
              : "+v"(acc[i][j]) : "v"(af[i]), "v"(bfr[j]));
    }
  }
  asm volatile("s_nop 7\n\ts_nop 7\n\ts_nop 7" ::);  // MFMA->VALU hazard guard

  const long orow = brow + wr * 64;
  const long ocol = bcol + wc * 64;
#pragma unroll
  for (int j = 0; j < 4; ++j) {
    const long c  = ocol + j * 16 + r16;
    const float bv = bias[c];
#pragma unroll
    for (int i = 0; i < 4; ++i) {
      const long r0 = orow + i * 16 + ((lane >> 4) << 2);
#pragma unroll
      for (int r = 0; r < 4; ++r) {
        float v = acc[i][j][r] + bv;
        const long idx = (r0 + r) * (long)N + c;
        if (EPI == 0)      outB[idx] = f2bf(v);
        else if (EPI == 1) outB[idx] = f2bf(fmaxf(v, 0.f));
        else               outF[idx] = v + res[idx];
      }
    }
  }
}

// ---------- bf16 MFMA GEMM 128x64 tile (for N=512: 2x the blocks) ----------
template <int EPI>
__global__ __launch_bounds__(256, 4)
void gemm64_kernel(const ushort_t* __restrict__ A, const ushort_t* __restrict__ Bt,
                   const float* __restrict__ bias, const float* res,
                   float* outF, ushort_t* outB, int M, int N, int K) {
  __shared__ __align__(16) ushort_t sA[128 * 64];
  __shared__ __align__(16) ushort_t sB[64 * 64];
  const int tid  = threadIdx.x;
  const int lane = tid & 63;
  const int w    = tid >> 6;
  const int wr   = w >> 1, wc = w & 1;     // 2x2 waves, each owns 64x32 of the 128x64 tile
  const long brow = (long)blockIdx.x * 128;
  const long bcol = (long)blockIdx.y * 64;
  const int r16 = lane & 15;
  const int kb8 = (lane >> 4) << 3;
  f32x4 acc[4][2] = {};

  for (int k0 = 0; k0 < K; k0 += 64) {
    __syncthreads();
#pragma unroll
    for (int i = 0; i < 4; ++i) {
      const int c  = i * 256 + tid;
      const int wb = i * 256 + (tid & ~63);
      gload_lds16(A + (brow + (c >> 3)) * (long)K + k0 + ((c & 7) << 3), &sA[(long)wb * 8]);
    }
#pragma unroll
    for (int i = 0; i < 2; ++i) {
      const int c  = i * 256 + tid;
      const int wb = i * 256 + (tid & ~63);
      gload_lds16(Bt + (bcol + (c >> 3)) * (long)K + k0 + ((c & 7) << 3), &sB[(long)wb * 8]);
    }
    __syncthreads();
#pragma unroll
    for (int kk = 0; kk < 64; kk += 32) {
      u32x4 af[4], bfr[2];
#pragma unroll
      for (int i = 0; i < 4; ++i)
        af[i] = *(const u32x4*)&sA[(wr * 64 + i * 16 + r16) * 64 + kk + kb8];
#pragma unroll
      for (int j = 0; j < 2; ++j)
        bfr[j] = *(const u32x4*)&sB[(wc * 32 + j * 16 + r16) * 64 + kk + kb8];
#pragma unroll
      for (int i = 0; i < 4; ++i)
#pragma unroll
        for (int j = 0; j < 2; ++j)
          asm("v_mfma_f32_16x16x32_bf16 %0, %1, %2, %0"
              : "+v"(acc[i][j]) : "v"(af[i]), "v"(bfr[j]));
    }
  }
  asm volatile("s_nop 7\n\ts_nop 7\n\ts_nop 7" ::);

  const long orow = brow + wr * 64;
  const long ocol = bcol + wc * 32;
#pragma unroll
  for (int j = 0; j < 2; ++j) {
    const long c  = ocol + j * 16 + r16;
    const float bv = bias[c];
#pragma unroll
    for (int i = 0; i < 4; ++i) {
      const long r0 = orow + i * 16 + ((lane >> 4) << 2);
#pragma unroll
      for (int r = 0; r < 4; ++r) {
        float v = acc[i][j][r] + bv;
        const long idx = (r0 + r) * (long)N + c;
        if (EPI == 0)      outB[idx] = f2bf(v);
        else if (EPI == 1) outB[idx] = f2bf(fmaxf(v, 0.f));
        else               outF[idx] = v + res[idx];
      }
    }
  }
}

// ---------- CSR build (counting sort by dst), both graphs fused ----------
__global__ void zero_kernel(int* p, int n) {
  int i = blockIdx.x * blockDim.x + threadIdx.x;
  if (i < n) p[i] = 0;
}
__global__ void hist2_kernel(const int* __restrict__ d0, const int* __restrict__ d1,
                             int* __restrict__ counts2, int E) {
  const int* d = blockIdx.y ? d1 : d0;
  int* c = counts2 + blockIdx.y * 8192;
  for (int e = blockIdx.x * blockDim.x + threadIdx.x; e < E; e += gridDim.x * blockDim.x)
    atomicAdd(&c[d[e]], 1);
}
__global__ void scan2_kernel(const int* __restrict__ counts2, int* __restrict__ rowstart2,
                             int* __restrict__ cursor2) {
  const int* counts = counts2 + blockIdx.x * 8192;
  int* rowstart = rowstart2 + blockIdx.x * 8193;
  int* cursor   = cursor2 + blockIdx.x * 8192;
  __shared__ int part[256];
  const int t = threadIdx.x;
  int loc[32];
  int s = 0;
  const int base = t * 32;
#pragma unroll
  for (int i = 0; i < 32; ++i) { loc[i] = counts[base + i]; s += loc[i]; }
  part[t] = s;
  __syncthreads();
  for (int off = 1; off < 256; off <<= 1) {
    int v2 = (t >= off) ? part[t - off] : 0;
    __syncthreads();
    part[t] += v2;
    __syncthreads();
  }
  int run = part[t] - s;   // exclusive prefix
#pragma unroll
  for (int i = 0; i < 32; ++i) { rowstart[base + i] = run; cursor[base + i] = run; run += loc[i]; }
  if (t == 255) rowstart[8192] = run;
}
__global__ void scatter2_kernel(const int* __restrict__ s0, const int* __restrict__ d0,
                                const int* __restrict__ s1, const int* __restrict__ d1,
                                int* __restrict__ cursor2,
                                int* __restrict__ o0, int* __restrict__ o1, int E) {
  const int* s = blockIdx.y ? s1 : s0;
  const int* d = blockIdx.y ? d1 : d0;
  int* cur = cursor2 + blockIdx.y * 8192;
  int* o   = blockIdx.y ? o1 : o0;
  for (int e = blockIdx.x * blockDim.x + threadIdx.x; e < E; e += gridDim.x * blockDim.x) {
    const int p = atomicAdd(&cur[d[e]], 1);
    o[p] = s[e];
  }
}

// ---------- graph attention: one wave per dst node, 4-wide x 2-stage pipeline ----------
#define ATT_LOADI(SD, EBASE)                                             \
  _Pragma("unroll") for (int j = 0; j < 4; ++j) {                        \
    int e = (EBASE) + j;                                                 \
    SD[j] = srcs[e < e1 ? e : e1 - 1];                                   \
  }
#define ATT_LOADG(KD, VD, SD)                                            \
  _Pragma("unroll") for (int j = 0; j < 4; ++j) {                        \
    const long ro = (long)SD[j] * ks + loff;                             \
    KD[j] = *(const u32x4*)(kb + ro);                                    \
    VD[j] = *(const u32x4*)(vb + ro);                                    \
  }
#define ATT_COMPUTE(GB, KF, VF)                                          \
  _Pragma("unroll") for (int j = 0; j < 4; ++j) {                        \
    f32x2 d2 = {0.f, 0.f};                                               \
    _Pragma("unroll") for (int u = 0; u < 4; ++u) {                      \
      f32x2 kp = {bflo(KF[j][u]), bfhi(KF[j][u])};                       \
      d2 += kp * q2[u];                                                  \
    }                                                                    \
    float dot = d2[0] + d2[1];                                           \
    dot += __shfl_xor(dot, 1);                                           \
    dot += __shfl_xor(dot, 2);                                           \
    dot += __shfl_xor(dot, 4);                                           \
    float sc = __expf(fminf(fmaxf(dot * 0.125f, -10.f), 10.f));          \
    sc = ((GB) + j < n) ? sc : 0.f;                                      \
    z += sc;                                                             \
    f32x2 s2 = {sc, sc};                                                 \
    _Pragma("unroll") for (int u = 0; u < 4; ++u) {                      \
      f32x2 vp = {bflo(VF[j][u]), bfhi(VF[j][u])};                       \
      av[u] += s2 * vp;                                                  \
    }                                                                    \
  }

__global__ __launch_bounds__(256)
void attend_kernel(const int* __restrict__ rowstart, const int* __restrict__ srcs,
                   const ushort_t* __restrict__ qb, int qs,
                   const ushort_t* __restrict__ kb, const ushort_t* __restrict__ vb, int ks,
                   ushort_t* __restrict__ ob) {
  const int d    = blockIdx.x * 4 + (threadIdx.x >> 6);
  const int lane = threadIdx.x & 63;           // lane covers cols lane*8..+7; head = lane>>3
  const int loff = lane * 8;
  const int e0 = rowstart[d], e1 = rowstart[d + 1];
  const int n  = e1 - e0;
  const u32x4 qv = *(const u32x4*)(qb + (long)d * qs + loff);
  f32x2 q2[4];
#pragma unroll
  for (int u = 0; u < 4; ++u) q2[u] = f32x2{bflo(qv[u]), bfhi(qv[u])};
  f32x2 av[4] = {};
  float z = 0.f;
  if (n > 0) {
    int sA4[4], sB4[4];
    u32x4 kA4[4], vA4[4], kB4[4], vB4[4];
    ATT_LOADI(sA4, e0);
    ATT_LOADI(sB4, e0 + 4);
    ATT_LOADG(kA4, vA4, sA4);
    const int ng = (n + 3) >> 2;
    const int NG = (ng + 1) & ~1;            // even # of groups; tail masked by sc=0
    for (int g = 0; g < NG; g += 2) {
      ATT_LOADG(kB4, vB4, sB4);              // issue group g+1 gathers
      ATT_LOADI(sA4, e0 + (g + 2) * 4);      // indices for group g+2
      ATT_COMPUTE(g * 4, kA4, vA4);          // compute group g
      ATT_LOADG(kA4, vA4, sA4);              // issue group g+2 gathers
      ATT_LOADI(sB4, e0 + (g + 3) * 4);      // indices for group g+3
      ATT_COMPUTE((g + 1) * 4, kB4, vB4);    // compute group g+1
    }
  }
  const float inv = 1.f / z;
  u32x4 o;
#pragma unroll
  for (int u = 0; u < 4; ++u) {
    unsigned int lo = f2bf(av[u][0] * inv);
    unsigned int hi = f2bf(av[u][1] * inv);
    o[u] = lo | (hi << 16);
  }
  *(u32x4*)(ob + (long)d * DD + loff) = o;
}

// ---------- host orchestration ----------
extern "C" void kernel_launch(void* const* d_in, const int* in_sizes, int n_in,
                              void* d_out, int out_size, void* d_ws, size_t ws_size,
                              hipStream_t stream) {
  const float* x    = (const float*)d_in[0];
  const float* mem  = (const float*)d_in[1];
  const float* ln0g = (const float*)d_in[2];  const float* ln0b = (const float*)d_in[3];
  const float* ln1g = (const float*)d_in[4];  const float* ln1b = (const float*)d_in[5];
  const float* ln2g = (const float*)d_in[6];  const float* ln2b = (const float*)d_in[7];
  const float* Wq = (const float*)d_in[8];   const float* bq = (const float*)d_in[9];
  const float* Wk = (const float*)d_in[10];  const float* bk = (const float*)d_in[11];
  const float* Wv = (const float*)d_in[12];  const float* bv = (const float*)d_in[13];
  const float* Wo = (const float*)d_in[14];  const float* bo = (const float*)d_in[15];
  const float* W1 = (const float*)d_in[16];  const float* b1 = (const float*)d_in[17];
  const float* W2 = (const float*)d_in[18];  const float* b2 = (const float*)d_in[19];
  const int* src_self  = (const int*)d_in[20];
  const int* dst_self  = (const int*)d_in[21];
  const int* src_cross = (const int*)d_in[22];
  const int* dst_cross = (const int*)d_in[23];
  const int E = in_sizes[20];
  float* out = (float*)d_out;

  char* wsp = (char*)d_ws;
  auto alloc = [&](size_t bytes) {
    char* p = wsp;
    wsp += (bytes + 255) & ~(size_t)255;
    return p;
  };
  // weights: Wqkv_t rows 0-511=Wq^T, 512-1023=Wk^T, 1024-1535=Wv^T (all [n][k], k=512)
  ushort_t* Wqkv_t = (ushort_t*)alloc((size_t)1536 * 512 * 2);
  ushort_t* Wo_t   = (ushort_t*)alloc((size_t)512 * 512 * 2);
  ushort_t* W1_t   = (ushort_t*)alloc((size_t)DFF * DD * 2);
  ushort_t* W2_t   = (ushort_t*)alloc((size_t)DD * DFF * 2);
  float*    bqkv   = (float*)alloc(1536 * 4);
  ushort_t* h_bf   = (ushort_t*)alloc((size_t)NN * DD * 2);
  ushort_t* mem_bf = (ushort_t*)alloc((size_t)MMM * DD * 2);
  ushort_t* buf1   = (ushort_t*)alloc((size_t)NN * DFF * 2);  // 32MB arena: qkv / q1+kv / ffh
  ushort_t* attn_bf= (ushort_t*)alloc((size_t)NN * DD * 2);
  int* counts2   = (int*)alloc(2 * 8192 * 4);
  int* rowstart2 = (int*)alloc(2 * 8193 * 4);
  int* cursor2   = (int*)alloc(2 * 8192 * 4);
  int* srcsA     = (int*)alloc((size_t)E * 4);
  int* srcsB     = (int*)alloc((size_t)E * 4);

  const dim3 B256(256);

  // ---- prep: weights, mem cast, both CSRs (input-only deps) ----
  TW4 tw{Wq, Wk, Wv, Wo, Wqkv_t, Wqkv_t + 512 * 512, Wqkv_t + 1024 * 512, Wo_t};
  transw4_kernel<<<dim3(16, 16, 4), dim3(32, 8), 0, stream>>>(tw);
  transw_kernel<<<dim3(64, 16), dim3(32, 8), 0, stream>>>(W1, W1_t, DD, DFF);
  transw_kernel<<<dim3(16, 64), dim3(32, 8), 0, stream>>>(W2, W2_t, DFF, DD);
  biascat_kernel<<<dim3(6), B256, 0, stream>>>(bq, bk, bv, bqkv);
  tobf_kernel<<<dim3(MMM * DD / 4 / 256), B256, 0, stream>>>(mem, mem_bf, MMM * DD / 4);
  zero_kernel<<<dim3(64), B256, 0, stream>>>(counts2, 2 * 8192);
  hist2_kernel<<<dim3(256, 2), B256, 0, stream>>>(dst_self, dst_cross, counts2, E);
  scan2_kernel<<<dim3(2), B256, 0, stream>>>(counts2, rowstart2, cursor2);
  scatter2_kernel<<<dim3(256, 2), B256, 0, stream>>>(src_self, dst_self, src_cross, dst_cross,
                                                     cursor2, srcsA, srcsB, E);

  auto gemm = [&](int mode, const ushort_t* Ap, const ushort_t* Btp, const float* biasp,
                  const float* resp, float* oF, ushort_t* oB, int M_, int N_, int K_) {
    if (N_ == 512) {                          // grid-starved shapes -> 128x64 tiles
      dim3 g(M_ / 128, N_ / 64);
      if (mode == 0)
        gemm64_kernel<0><<<g, B256, 0, stream>>>(Ap, Btp, biasp, resp, oF, oB, M_, N_, K_);
      else if (mode == 1)
        gemm64_kernel<1><<<g, B256, 0, stream>>>(Ap, Btp, biasp, resp, oF, oB, M_, N_, K_);
      else
        gemm64_kernel<2><<<g, B256, 0, stream>>>(Ap, Btp, biasp, resp, oF, oB, M_, N_, K_);
    } else {
      dim3 g(M_ / 128, N_ / 128);
      if (mode == 0)
        gemm_kernel<0><<<g, B256, 0, stream>>>(Ap, Btp, biasp, resp, oF, oB, M_, N_, K_);
      else if (mode == 1)
        gemm_kernel<1><<<g, B256, 0, stream>>>(Ap, Btp, biasp, resp, oF, oB, M_, N_, K_);
      else
        gemm_kernel<2><<<g, B256, 0, stream>>>(Ap, Btp, biasp, resp, oF, oB, M_, N_, K_);
    }
  };

  // ---- sublayer 0: self-attention ----
  ln_kernel<<<dim3(NN / 4), B256, 0, stream>>>(x, ln0g, ln0b, h_bf);
  gemm(0, h_bf, Wqkv_t, bqkv, nullptr, nullptr, buf1, NN, 1536, DD);   // fused q|k|v
  attend_kernel<<<dim3(NN / 4), B256, 0, stream>>>(rowstart2, srcsA,
      buf1, 1536, buf1 + 512, buf1 + 1024, 1536, attn_bf);
  gemm(2, attn_bf, Wo_t, bo, x, out, nullptr, NN, DD, DD);             // out = x + attn@Wo+bo

  // ---- sublayer 1: cross-attention ----
  ln_kernel<<<dim3(NN / 4), B256, 0, stream>>>(out, ln1g, ln1b, h_bf);
  {
    ushort_t* q1 = buf1;                       // [8192][512]
    ushort_t* kv = buf1 + (size_t)NN * 512;    // [8192][1024] (k|v)
    gemm(0, h_bf, Wqkv_t, bqkv, nullptr, nullptr, q1, NN, 512, DD);                    // q only
    gemm(0, mem_bf, Wqkv_t + 512 * 512, bqkv + 512, nullptr, nullptr, kv, MMM, 1024, DD); // k|v (no LN)
    attend_kernel<<<dim3(NN / 4), B256, 0, stream>>>(rowstart2 + 8193, srcsB,
        q1, 512, kv, kv + 512, 1024, attn_bf);
  }
  gemm(2, attn_bf, Wo_t, bo, out, out, nullptr, NN, DD, DD);           // out += attn@Wo+bo

  // ---- sublayer 2: feed-forward ----
  ln_kernel<<<dim3(NN / 4), B256, 0, stream>>>(out, ln2g, ln2b, h_bf);
  gemm(1, h_bf, W1_t, b1, nullptr, nullptr, buf1, NN, DFF, DD);        // relu, bf16 out
  gemm(2, buf1, W2_t, b2, out, out, nullptr, NN, DD, DFF);             // out += ff@W2+b2

  (void)n_in; (void)out_size; (void)ws_size; (void)in_sizes;
}